// Round 8
// baseline (1071.808 us; speedup 1.0000x reference)
//
#include <hip/hip_runtime.h>

// TRW-P message passing, MI355X (gfx950). CORRECTNESS-FIRST variant:
// no DPP / permlane asm / readlane hybrid / deferred norm / pair fusion.
// unary (4,1,21,224,224) f32, edge_weights (4,4,224,224) f32, V (21,21) f32.
// out (4,1,21,224,224) f32.
// Workspace (floats): msgs[4] (b,y,x,k) + unary_t (b,y,x,k) = 5 * 4214784.
#define NPIX_B   50176      // 224*224
#define NELEM    4214784    // 4*224*224*21
#define KK       21

__device__ __forceinline__ float min3f(float a, float b, float c) {
    return fminf(fminf(a, b), c);
}

// ---------------- transpose unary (b,k,y,x) -> (b,y,x,k) ----------------
__global__ __launch_bounds__(256)
void transpose_unary(const float* __restrict__ src, float* __restrict__ dst)
{
    __shared__ float lds[224 * KK];
    int blk = blockIdx.x;           // (b,y)
    int b = blk / 224, y = blk % 224;
    for (int idx = threadIdx.x; idx < 224 * KK; idx += 256) {
        int kk = idx / 224, x = idx - kk * 224;
        lds[x * KK + kk] = src[(size_t)b * (KK * NPIX_B) + kk * NPIX_B + y * 224 + x];
    }
    __syncthreads();
    float* d2 = dst + (size_t)(b * 224 + y) * 224 * KK;
    for (int idx = threadIdx.x; idx < 224 * KK; idx += 256) d2[idx] = lds[idx];
}

// ---------------- one directional sweep (224 serial steps) ----------------
// One row (b, mm) per 64-lane wave. lane holds label k = min(lane&31, 20);
// lanes 21..31 / 53..63 duplicate k=20 (same address AND value on stores).
// Per step (matches reference _sweep exactly, direct normalization):
//   tmp[k'] = base[i-1][k'] + rho * n[i-1][k']
//   m_raw[k] = min_k' (tmp[k'] + ew[i] * V[k',k])
//   n[i] = m_raw - min_k(m_raw)
template<int D, bool VA, bool VB, bool VO, bool FUSE>
__global__ __launch_bounds__(64, 1)
void sweep_kernel(const float* __restrict__ unt,
                  const float* __restrict__ msA,   // msgs[other1]
                  const float* __restrict__ msB,   // msgs[other2]
                  const float* __restrict__ msO,   // msgs[opp]
                  float*       __restrict__ msD,   // msgs[D] (written unless FUSE)
                  const float* __restrict__ ewp,   // edge_weights (4,4,224,224)
                  const float* __restrict__ Vp,    // (21,21)
                  float*       __restrict__ outp)  // final output (FUSE only)
{
    const int lane = threadIdx.x;
    const int r    = blockIdx.x;         // 0..895
    const int b    = r / 224;
    const int mm   = r % 224;            // y for D=0,1 ; x for D=2,3
    const int kk   = lane & 31;
    const int k    = (kk < KK) ? kk : (KK - 1);

    float Vk[KK];                         // V[k'][k] for all k'
#pragma unroll
    for (int t = 0; t < KK; ++t) Vk[t] = Vp[t * KK + k];

    int pix0, sp;
    if (D == 0)      { pix0 = (b * 224 + mm) * 224;        sp = 1;    }
    else if (D == 1) { pix0 = (b * 224 + mm) * 224 + 223;  sp = -1;   }
    else if (D == 2) { pix0 = b * NPIX_B + mm;             sp = 224;  }
    else             { pix0 = b * NPIX_B + 223 * 224 + mm; sp = -224; }
    const int ewb = (b * 4 + D) * NPIX_B + (pix0 - b * NPIX_B);

    // prefetch: pre = rho*(un+ma+mb+mo) - mo (= base[i-1]); s3 for FUSE output
    float Apre[8], Aew[8], As3[8] = {};
    float Bpre[8], Bew[8], Bs3[8] = {};

#define LDC(P, c)                                                         \
    {                                                                     \
        _Pragma("unroll")                                                 \
        for (int t = 0; t < 8; ++t) {                                     \
            int i  = (c) * 8 + t;                                         \
            int ib = i - 1; if (ib < 0) ib = 0;                           \
            int o  = (pix0 + ib * sp) * KK + k;                           \
            float un = unt[o];                                            \
            float ma = VA ? msA[o] : 0.0f;                                \
            float mb = VB ? msB[o] : 0.0f;                                \
            float mo = VO ? msO[o] : 0.0f;                                \
            float s  = (un + ma) + (mb + mo);                             \
            P##pre[t] = fmaf(0.5f, s, -mo);                               \
            if constexpr (FUSE) P##s3[t] = s;                             \
            P##ew[t] = ewp[ewb + i * sp];                                 \
        }                                                                 \
    }

    float n = 0.0f, nprev = 0.0f;

    auto step = [&](float pre, float s3v, float ewi, int i) {
        if constexpr (FUSE) {                 // D==3: out at scan pos i-1 -> y=224-i
            if (i > 0)
                outp[((b * KK + k) * 224 + (224 - i)) * 224 + mm] = s3v + nprev;
        }
        if (i == 0) {
            n = 0.0f; nprev = 0.0f;
            if (!FUSE) msD[pix0 * KK + k] = 0.0f;
            return;
        }
        float tmp = fmaf(0.5f, n, pre);       // base_prev + rho*n_prev
        float c[KK];
#pragma unroll
        for (int t = 0; t < KK; ++t)
            c[t] = fmaf(ewi, Vk[t], __shfl(tmp, t, 64));
        float m0 = min3f(c[0],  c[1],  c[2]);
        float m1 = min3f(c[3],  c[4],  c[5]);
        float m2 = min3f(c[6],  c[7],  c[8]);
        float m3 = min3f(c[9],  c[10], c[11]);
        float m4 = min3f(c[12], c[13], c[14]);
        float m5 = min3f(c[15], c[16], c[17]);
        float m6 = min3f(c[18], c[19], c[20]);
        float mv = min3f(min3f(m0, m1, m2), min3f(m3, m4, m5), m6);
        // direct normalization: min over labels == min over 64 lanes (dups only)
        float v = mv;
        v = fminf(v, __shfl_xor(v, 32, 64));
        v = fminf(v, __shfl_xor(v, 16, 64));
        v = fminf(v, __shfl_xor(v, 8, 64));
        v = fminf(v, __shfl_xor(v, 4, 64));
        v = fminf(v, __shfl_xor(v, 2, 64));
        v = fminf(v, __shfl_xor(v, 1, 64));
        n = mv - v;
        if (!FUSE) msD[(pix0 + i * sp) * KK + k] = n;
        nprev = n;
    };

    LDC(A, 0);
    for (int cc = 0; cc < 28; cc += 2) {
        LDC(B, cc + 1);
#pragma unroll
        for (int t = 0; t < 8; ++t)
            step(Apre[t], As3[t], Aew[t], cc * 8 + t);
        if (cc + 2 < 28) LDC(A, cc + 2);
#pragma unroll
        for (int t = 0; t < 8; ++t)
            step(Bpre[t], Bs3[t], Bew[t], (cc + 1) * 8 + t);
    }
    if constexpr (FUSE) {
        // tail: scan pos 223 -> pixel y=0, x=mm
        int o = (pix0 + 223 * sp) * KK + k;
        float s3 = (unt[o] + msA[o]) + (msB[o] + msO[o]);
        outp[((b * KK + k) * 224 + 0) * 224 + mm] = s3 + nprev;
    }
#undef LDC
    (void)lane;
}

extern "C" void kernel_launch(void* const* d_in, const int* in_sizes, int n_in,
                              void* d_out, int out_size, void* d_ws, size_t ws_size,
                              hipStream_t stream)
{
    const float* unary = (const float*)d_in[0];
    const float* ew    = (const float*)d_in[1];
    const float* V     = (const float*)d_in[2];
    float* out = (float*)d_out;

    float* w   = (float*)d_ws;
    float* ms0 = w;
    float* ms1 = w + (size_t)NELEM;
    float* ms2 = w + (size_t)NELEM * 2;
    float* ms3 = w + (size_t)NELEM * 3;
    float* unt = w + (size_t)NELEM * 4;

    transpose_unary<<<dim3(896), dim3(256), 0, stream>>>(unary, unt);

    dim3 gS(896), bS(64);
    // iteration 0 (unwritten messages are provably zero -> elide loads;
    // ws is 0xAA-poisoned so elision is REQUIRED, not an optimization)
    sweep_kernel<0, false, false, false, false><<<gS, bS, 0, stream>>>(unt, ms2, ms3, ms1, ms0, ew, V, nullptr);
    sweep_kernel<1, false, false, true,  false><<<gS, bS, 0, stream>>>(unt, ms2, ms3, ms0, ms1, ew, V, nullptr);
    sweep_kernel<2, true,  true,  false, false><<<gS, bS, 0, stream>>>(unt, ms0, ms1, ms3, ms2, ew, V, nullptr);
    sweep_kernel<3, true,  true,  true,  false><<<gS, bS, 0, stream>>>(unt, ms0, ms1, ms2, ms3, ew, V, nullptr);
    // iteration 1 (all valid); last sweep fuses the final output
    sweep_kernel<0, true,  true,  true,  false><<<gS, bS, 0, stream>>>(unt, ms2, ms3, ms1, ms0, ew, V, nullptr);
    sweep_kernel<1, true,  true,  true,  false><<<gS, bS, 0, stream>>>(unt, ms2, ms3, ms0, ms1, ew, V, nullptr);
    sweep_kernel<2, true,  true,  true,  false><<<gS, bS, 0, stream>>>(unt, ms0, ms1, ms3, ms2, ew, V, nullptr);
    sweep_kernel<3, true,  true,  true,  true ><<<gS, bS, 0, stream>>>(unt, ms0, ms1, ms2, ms3, ew, V, out);
}

// Round 9
// 753.481 us; speedup vs baseline: 1.4225x; 1.4225x over previous
//
#include <hip/hip_runtime.h>

// TRW-P message passing, MI355X (gfx950).
// Round 9 = round-8 passing anchor + (a) readlane broadcast (no LDS ops on
// the critical path), (b) deferred normalization (norm chain off-path).
// unary (4,1,21,224,224) f32, edge_weights (4,4,224,224) f32, V (21,21) f32.
// out (4,1,21,224,224) f32.
// Workspace (floats): msgs[4] (b,y,x,k) + unary_t (b,y,x,k) = 5 * 4214784.
#define NPIX_B   50176      // 224*224
#define NELEM    4214784    // 4*224*224*21
#define KK       21

__device__ __forceinline__ float min3f(float a, float b, float c) {
    return fminf(fminf(a, b), c);
}

// ---------------- transpose unary (b,k,y,x) -> (b,y,x,k) ----------------
__global__ __launch_bounds__(256)
void transpose_unary(const float* __restrict__ src, float* __restrict__ dst)
{
    __shared__ float lds[224 * KK];
    int blk = blockIdx.x;           // (b,y)
    int b = blk / 224, y = blk % 224;
    for (int idx = threadIdx.x; idx < 224 * KK; idx += 256) {
        int kk = idx / 224, x = idx - kk * 224;
        lds[x * KK + kk] = src[(size_t)b * (KK * NPIX_B) + kk * NPIX_B + y * 224 + x];
    }
    __syncthreads();
    float* d2 = dst + (size_t)(b * 224 + y) * 224 * KK;
    for (int idx = threadIdx.x; idx < 224 * KK; idx += 256) d2[idx] = lds[idx];
}

// ---------------- one directional sweep (224 serial steps) ----------------
// One row (b, mm) per 64-lane wave. lane holds label k = min(lane&31, 20);
// dup lanes compute identical values (uniform ew, same per-k loads) so all
// stores are same-address-same-value and the 64-lane min == label min.
// Recurrence runs UN-normalized: u_i = S(u_{i-1}); stored n_i = u_i - min(u_i)
// equals the reference message exactly (min-plus shift invariance: the
// uniform shift c scales by rho per step and cancels in the normalizer).
// Per step:
//   tmp[k'] = base[i-1][k'] + rho * u[i-1][k']       (base folded into 'pre')
//   u_i[k]  = min_k' (tmp[k'] + ew[i] * V[k',k])     (readlane broadcast)
//   n_i     = u_i - min_k(u_i)                        (shfl_xor, OFF the path)
template<int D, bool VA, bool VB, bool VO, bool FUSE>
__global__ __launch_bounds__(64, 1)
void sweep_kernel(const float* __restrict__ unt,
                  const float* __restrict__ msA,   // msgs[other1]
                  const float* __restrict__ msB,   // msgs[other2]
                  const float* __restrict__ msO,   // msgs[opp]
                  float*       __restrict__ msD,   // msgs[D] (written unless FUSE)
                  const float* __restrict__ ewp,   // edge_weights (4,4,224,224)
                  const float* __restrict__ Vp,    // (21,21)
                  float*       __restrict__ outp)  // final output (FUSE only)
{
    const int lane = threadIdx.x;
    const int r    = blockIdx.x;         // 0..895
    const int b    = r / 224;
    const int mm   = r % 224;            // y for D=0,1 ; x for D=2,3
    const int kk   = lane & 31;
    const int k    = (kk < KK) ? kk : (KK - 1);

    float Vk[KK];                         // V[k'][k] for all k'
#pragma unroll
    for (int t = 0; t < KK; ++t) Vk[t] = Vp[t * KK + k];

    int pix0, sp;
    if (D == 0)      { pix0 = (b * 224 + mm) * 224;        sp = 1;    }
    else if (D == 1) { pix0 = (b * 224 + mm) * 224 + 223;  sp = -1;   }
    else if (D == 2) { pix0 = b * NPIX_B + mm;             sp = 224;  }
    else             { pix0 = b * NPIX_B + 223 * 224 + mm; sp = -224; }
    const int ewb = (b * 4 + D) * NPIX_B + (pix0 - b * NPIX_B);

    // prefetch: pre = rho*(un+ma+mb+mo) - mo (= base[i-1]); s3 for FUSE output
    float Apre[8], Aew[8], As3[8] = {};
    float Bpre[8], Bew[8], Bs3[8] = {};

#define LDC(P, c)                                                         \
    {                                                                     \
        _Pragma("unroll")                                                 \
        for (int t = 0; t < 8; ++t) {                                     \
            int i  = (c) * 8 + t;                                         \
            int ib = i - 1; if (ib < 0) ib = 0;                           \
            int o  = (pix0 + ib * sp) * KK + k;                           \
            float un = unt[o];                                            \
            float ma = VA ? msA[o] : 0.0f;                                \
            float mb = VB ? msB[o] : 0.0f;                                \
            float mo = VO ? msO[o] : 0.0f;                                \
            float s  = (un + ma) + (mb + mo);                             \
            P##pre[t] = fmaf(0.5f, s, -mo);                               \
            if constexpr (FUSE) P##s3[t] = s;                             \
            P##ew[t] = ewp[ewb + i * sp];                                 \
        }                                                                 \
    }

    float u = 0.0f, nprev = 0.0f;

    auto step = [&](float pre, float s3v, float ewi, int i) {
        if constexpr (FUSE) {                 // D==3: out at scan pos i-1 -> y=224-i
            if (i > 0)
                outp[((b * KK + k) * 224 + (224 - i)) * 224 + mm] = s3v + nprev;
        }
        if (i == 0) {
            u = 0.0f; nprev = 0.0f;
            if (!FUSE) msD[pix0 * KK + k] = 0.0f;
            return;
        }
        float tmp = fmaf(0.5f, u, pre);       // base_prev + rho*u_prev
        int   ti  = __float_as_int(tmp);
        // broadcast tmp[k'] to all lanes via readlane (VALU pipe, no LDS)
        float c[KK];
#pragma unroll
        for (int t = 0; t < KK; ++t)
            c[t] = fmaf(ewi, Vk[t],
                        __int_as_float(__builtin_amdgcn_readlane(ti, t)));
        float m0 = min3f(c[0],  c[1],  c[2]);
        float m1 = min3f(c[3],  c[4],  c[5]);
        float m2 = min3f(c[6],  c[7],  c[8]);
        float m3 = min3f(c[9],  c[10], c[11]);
        float m4 = min3f(c[12], c[13], c[14]);
        float m5 = min3f(c[15], c[16], c[17]);
        float m6 = min3f(c[18], c[19], c[20]);
        u = min3f(min3f(m0, m1, m2), min3f(m3, m4, m5), m6);
        // deferred normalization (off the u-critical-path):
        float v = u;
        v = fminf(v, __shfl_xor(v, 32, 64));
        v = fminf(v, __shfl_xor(v, 16, 64));
        v = fminf(v, __shfl_xor(v, 8, 64));
        v = fminf(v, __shfl_xor(v, 4, 64));
        v = fminf(v, __shfl_xor(v, 2, 64));
        v = fminf(v, __shfl_xor(v, 1, 64));
        float n = u - v;
        if (!FUSE) msD[(pix0 + i * sp) * KK + k] = n;
        nprev = n;
    };

    LDC(A, 0);
    for (int cc = 0; cc < 28; cc += 2) {
        LDC(B, cc + 1);
#pragma unroll
        for (int t = 0; t < 8; ++t)
            step(Apre[t], As3[t], Aew[t], cc * 8 + t);
        if (cc + 2 < 28) LDC(A, cc + 2);
#pragma unroll
        for (int t = 0; t < 8; ++t)
            step(Bpre[t], Bs3[t], Bew[t], (cc + 1) * 8 + t);
    }
    if constexpr (FUSE) {
        // tail: scan pos 223 -> pixel y=0, x=mm
        int o = (pix0 + 223 * sp) * KK + k;
        float s3 = (unt[o] + msA[o]) + (msB[o] + msO[o]);
        outp[((b * KK + k) * 224 + 0) * 224 + mm] = s3 + nprev;
    }
#undef LDC
    (void)lane;
}

extern "C" void kernel_launch(void* const* d_in, const int* in_sizes, int n_in,
                              void* d_out, int out_size, void* d_ws, size_t ws_size,
                              hipStream_t stream)
{
    const float* unary = (const float*)d_in[0];
    const float* ew    = (const float*)d_in[1];
    const float* V     = (const float*)d_in[2];
    float* out = (float*)d_out;

    float* w   = (float*)d_ws;
    float* ms0 = w;
    float* ms1 = w + (size_t)NELEM;
    float* ms2 = w + (size_t)NELEM * 2;
    float* ms3 = w + (size_t)NELEM * 3;
    float* unt = w + (size_t)NELEM * 4;

    transpose_unary<<<dim3(896), dim3(256), 0, stream>>>(unary, unt);

    dim3 gS(896), bS(64);
    // iteration 0 (unwritten messages are provably zero -> elide loads;
    // ws is 0xAA-poisoned so elision is REQUIRED, not an optimization)
    sweep_kernel<0, false, false, false, false><<<gS, bS, 0, stream>>>(unt, ms2, ms3, ms1, ms0, ew, V, nullptr);
    sweep_kernel<1, false, false, true,  false><<<gS, bS, 0, stream>>>(unt, ms2, ms3, ms0, ms1, ew, V, nullptr);
    sweep_kernel<2, true,  true,  false, false><<<gS, bS, 0, stream>>>(unt, ms0, ms1, ms3, ms2, ew, V, nullptr);
    sweep_kernel<3, true,  true,  true,  false><<<gS, bS, 0, stream>>>(unt, ms0, ms1, ms2, ms3, ew, V, nullptr);
    // iteration 1 (all valid); last sweep fuses the final output
    sweep_kernel<0, true,  true,  true,  false><<<gS, bS, 0, stream>>>(unt, ms2, ms3, ms1, ms0, ew, V, nullptr);
    sweep_kernel<1, true,  true,  true,  false><<<gS, bS, 0, stream>>>(unt, ms2, ms3, ms0, ms1, ew, V, nullptr);
    sweep_kernel<2, true,  true,  true,  false><<<gS, bS, 0, stream>>>(unt, ms0, ms1, ms3, ms2, ew, V, nullptr);
    sweep_kernel<3, true,  true,  true,  true ><<<gS, bS, 0, stream>>>(unt, ms0, ms1, ms2, ms3, ew, V, out);
}

// Round 10
// 673.226 us; speedup vs baseline: 1.5920x; 1.1192x over previous
//
#include <hip/hip_runtime.h>

// TRW-P message passing, MI355X (gfx950).
// Round 10 = round-9 + LDS-free normalization:
//   min_k u[k] == min_k' fma(ew, Vmin[k'], tmp[k'])   (ew>=0, fma monotone)
// so the norm is computed per-lane from the SGPR-broadcast tmp[] — the
// 6-deep shfl_xor chain (6 serialized ~120cy LDS latencies/step) vanishes.
// unary (4,1,21,224,224) f32, edge_weights (4,4,224,224) f32, V (21,21) f32.
// out (4,1,21,224,224) f32.
// Workspace (floats): msgs[4] (b,y,x,k) + unary_t (b,y,x,k) = 5 * 4214784.
#define NPIX_B   50176      // 224*224
#define NELEM    4214784    // 4*224*224*21
#define KK       21

__device__ __forceinline__ float min3f(float a, float b, float c) {
    return fminf(fminf(a, b), c);
}

// ---------------- transpose unary (b,k,y,x) -> (b,y,x,k) ----------------
__global__ __launch_bounds__(256)
void transpose_unary(const float* __restrict__ src, float* __restrict__ dst)
{
    __shared__ float lds[224 * KK];
    int blk = blockIdx.x;           // (b,y)
    int b = blk / 224, y = blk % 224;
    for (int idx = threadIdx.x; idx < 224 * KK; idx += 256) {
        int kk = idx / 224, x = idx - kk * 224;
        lds[x * KK + kk] = src[(size_t)b * (KK * NPIX_B) + kk * NPIX_B + y * 224 + x];
    }
    __syncthreads();
    float* d2 = dst + (size_t)(b * 224 + y) * 224 * KK;
    for (int idx = threadIdx.x; idx < 224 * KK; idx += 256) d2[idx] = lds[idx];
}

// ---------------- one directional sweep (224 serial steps) ----------------
// One row (b, mm) per 64-lane wave. lane holds label k = min(lane&31, 20);
// dup lanes compute identical values (uniform ew, same per-k loads) so all
// stores are same-address-same-value.
// Recurrence runs UN-normalized: u_i = S(u_{i-1}); stored n_i = u_i - min_k(u_i)
// equals the reference message exactly (min-plus shift invariance).
// Per step (all VALU, no cross-lane after the readlane broadcasts):
//   tmp[k'] = base[i-1][k'] + rho*u[i-1][k']            (base folded in 'pre')
//   u_i[k]  = min_k' fma(ew_i, V[k',k],  tmp[k'])
//   minu    = min_k' fma(ew_i, Vmin[k'], tmp[k'])       (== min_k u_i, exact)
//   n_i     = u_i - minu
template<int D, bool VA, bool VB, bool VO, bool FUSE>
__global__ __launch_bounds__(64, 1)
void sweep_kernel(const float* __restrict__ unt,
                  const float* __restrict__ msA,   // msgs[other1]
                  const float* __restrict__ msB,   // msgs[other2]
                  const float* __restrict__ msO,   // msgs[opp]
                  float*       __restrict__ msD,   // msgs[D] (written unless FUSE)
                  const float* __restrict__ ewp,   // edge_weights (4,4,224,224)
                  const float* __restrict__ Vp,    // (21,21)
                  float*       __restrict__ outp)  // final output (FUSE only)
{
    const int lane = threadIdx.x;
    const int r    = blockIdx.x;         // 0..895
    const int b    = r / 224;
    const int mm   = r % 224;            // y for D=0,1 ; x for D=2,3
    const int kk   = lane & 31;
    const int k    = (kk < KK) ? kk : (KK - 1);

    float Vk[KK];                         // V[k'][k] for all k'
#pragma unroll
    for (int t = 0; t < KK; ++t) Vk[t] = Vp[t * KK + k];
    float Vmin[KK];                       // Vmin[k'] = min_k V[k'][k] (uniform)
#pragma unroll
    for (int t = 0; t < KK; ++t) {
        float mv = Vp[t * KK + 0];
#pragma unroll
        for (int q = 1; q < KK; ++q) mv = fminf(mv, Vp[t * KK + q]);
        Vmin[t] = mv;
    }

    int pix0, sp;
    if (D == 0)      { pix0 = (b * 224 + mm) * 224;        sp = 1;    }
    else if (D == 1) { pix0 = (b * 224 + mm) * 224 + 223;  sp = -1;   }
    else if (D == 2) { pix0 = b * NPIX_B + mm;             sp = 224;  }
    else             { pix0 = b * NPIX_B + 223 * 224 + mm; sp = -224; }
    const int ewb = (b * 4 + D) * NPIX_B + (pix0 - b * NPIX_B);

    // prefetch: pre = rho*(un+ma+mb+mo) - mo (= base[i-1]); s3 for FUSE output
    float Apre[8], Aew[8], As3[8] = {};
    float Bpre[8], Bew[8], Bs3[8] = {};

#define LDC(P, c)                                                         \
    {                                                                     \
        _Pragma("unroll")                                                 \
        for (int t = 0; t < 8; ++t) {                                     \
            int i  = (c) * 8 + t;                                         \
            int ib = i - 1; if (ib < 0) ib = 0;                           \
            int o  = (pix0 + ib * sp) * KK + k;                           \
            float un = unt[o];                                            \
            float ma = VA ? msA[o] : 0.0f;                                \
            float mb = VB ? msB[o] : 0.0f;                                \
            float mo = VO ? msO[o] : 0.0f;                                \
            float s  = (un + ma) + (mb + mo);                             \
            P##pre[t] = fmaf(0.5f, s, -mo);                               \
            if constexpr (FUSE) P##s3[t] = s;                             \
            P##ew[t] = ewp[ewb + i * sp];                                 \
        }                                                                 \
    }

    float u = 0.0f, nprev = 0.0f;

    auto step = [&](float pre, float s3v, float ewi, int i) {
        if constexpr (FUSE) {                 // D==3: out at scan pos i-1 -> y=224-i
            if (i > 0)
                outp[((b * KK + k) * 224 + (224 - i)) * 224 + mm] = s3v + nprev;
        }
        if (i == 0) {
            u = 0.0f; nprev = 0.0f;
            if (!FUSE) msD[pix0 * KK + k] = 0.0f;
            return;
        }
        float tmp = fmaf(0.5f, u, pre);       // base_prev + rho*u_prev
        int   ti  = __float_as_int(tmp);
        float c[KK], d[KK];
#pragma unroll
        for (int t = 0; t < KK; ++t) {
            float bt = __int_as_float(__builtin_amdgcn_readlane(ti, t));
            c[t] = fmaf(ewi, Vk[t],   bt);
            d[t] = fmaf(ewi, Vmin[t], bt);
        }
        float c0 = min3f(c[0],  c[1],  c[2]);
        float c1 = min3f(c[3],  c[4],  c[5]);
        float c2 = min3f(c[6],  c[7],  c[8]);
        float c3 = min3f(c[9],  c[10], c[11]);
        float c4 = min3f(c[12], c[13], c[14]);
        float c5 = min3f(c[15], c[16], c[17]);
        float c6 = min3f(c[18], c[19], c[20]);
        u = min3f(min3f(c0, c1, c2), min3f(c3, c4, c5), c6);
        float d0 = min3f(d[0],  d[1],  d[2]);
        float d1 = min3f(d[3],  d[4],  d[5]);
        float d2 = min3f(d[6],  d[7],  d[8]);
        float d3 = min3f(d[9],  d[10], d[11]);
        float d4 = min3f(d[12], d[13], d[14]);
        float d5 = min3f(d[15], d[16], d[17]);
        float d6 = min3f(d[18], d[19], d[20]);
        float minu = min3f(min3f(d0, d1, d2), min3f(d3, d4, d5), d6);
        float n = u - minu;                   // == u - min_k(u), bit-exact
        if (!FUSE) msD[(pix0 + i * sp) * KK + k] = n;
        nprev = n;
    };

    LDC(A, 0);
    for (int cc = 0; cc < 28; cc += 2) {
        LDC(B, cc + 1);
#pragma unroll
        for (int t = 0; t < 8; ++t)
            step(Apre[t], As3[t], Aew[t], cc * 8 + t);
        if (cc + 2 < 28) LDC(A, cc + 2);
#pragma unroll
        for (int t = 0; t < 8; ++t)
            step(Bpre[t], Bs3[t], Bew[t], (cc + 1) * 8 + t);
    }
    if constexpr (FUSE) {
        // tail: scan pos 223 -> pixel y=0, x=mm
        int o = (pix0 + 223 * sp) * KK + k;
        float s3 = (unt[o] + msA[o]) + (msB[o] + msO[o]);
        outp[((b * KK + k) * 224 + 0) * 224 + mm] = s3 + nprev;
    }
#undef LDC
    (void)lane;
}

extern "C" void kernel_launch(void* const* d_in, const int* in_sizes, int n_in,
                              void* d_out, int out_size, void* d_ws, size_t ws_size,
                              hipStream_t stream)
{
    const float* unary = (const float*)d_in[0];
    const float* ew    = (const float*)d_in[1];
    const float* V     = (const float*)d_in[2];
    float* out = (float*)d_out;

    float* w   = (float*)d_ws;
    float* ms0 = w;
    float* ms1 = w + (size_t)NELEM;
    float* ms2 = w + (size_t)NELEM * 2;
    float* ms3 = w + (size_t)NELEM * 3;
    float* unt = w + (size_t)NELEM * 4;

    transpose_unary<<<dim3(896), dim3(256), 0, stream>>>(unary, unt);

    dim3 gS(896), bS(64);
    // iteration 0 (unwritten messages are provably zero -> elide loads;
    // ws is 0xAA-poisoned so elision is REQUIRED, not an optimization)
    sweep_kernel<0, false, false, false, false><<<gS, bS, 0, stream>>>(unt, ms2, ms3, ms1, ms0, ew, V, nullptr);
    sweep_kernel<1, false, false, true,  false><<<gS, bS, 0, stream>>>(unt, ms2, ms3, ms0, ms1, ew, V, nullptr);
    sweep_kernel<2, true,  true,  false, false><<<gS, bS, 0, stream>>>(unt, ms0, ms1, ms3, ms2, ew, V, nullptr);
    sweep_kernel<3, true,  true,  true,  false><<<gS, bS, 0, stream>>>(unt, ms0, ms1, ms2, ms3, ew, V, nullptr);
    // iteration 1 (all valid); last sweep fuses the final output
    sweep_kernel<0, true,  true,  true,  false><<<gS, bS, 0, stream>>>(unt, ms2, ms3, ms1, ms0, ew, V, nullptr);
    sweep_kernel<1, true,  true,  true,  false><<<gS, bS, 0, stream>>>(unt, ms2, ms3, ms0, ms1, ew, V, nullptr);
    sweep_kernel<2, true,  true,  true,  false><<<gS, bS, 0, stream>>>(unt, ms0, ms1, ms3, ms2, ew, V, nullptr);
    sweep_kernel<3, true,  true,  true,  true ><<<gS, bS, 0, stream>>>(unt, ms0, ms1, ms2, ms3, ew, V, out);
}

// Round 11
// 652.739 us; speedup vs baseline: 1.6420x; 1.0314x over previous
//
#include <hip/hip_runtime.h>

// TRW-P message passing, MI355X (gfx950).
// Round 11 = round-10 + duplicate-lane repurposing: lanes kk>=21 load
// Vk[t]:=Vmin[t], so the ONE fma+min3 tree computes u[k] (lanes 0..20) AND
// minu = min_k u (lanes 21..31) simultaneously; the separate d[]-tree of
// round 10 (21 fma + 14 min) is deleted. minu via readlane(u, 21).
// unary (4,1,21,224,224) f32, edge_weights (4,4,224,224) f32, V (21,21) f32.
// out (4,1,21,224,224) f32.
// Workspace (floats): msgs[4] (b,y,x,k) + unary_t (b,y,x,k) = 5 * 4214784.
#define NPIX_B   50176      // 224*224
#define NELEM    4214784    // 4*224*224*21
#define KK       21

__device__ __forceinline__ float min3f(float a, float b, float c) {
    return fminf(fminf(a, b), c);
}

// ---------------- transpose unary (b,k,y,x) -> (b,y,x,k) ----------------
__global__ __launch_bounds__(256)
void transpose_unary(const float* __restrict__ src, float* __restrict__ dst)
{
    __shared__ float lds[224 * KK];
    int blk = blockIdx.x;           // (b,y)
    int b = blk / 224, y = blk % 224;
    for (int idx = threadIdx.x; idx < 224 * KK; idx += 256) {
        int kk = idx / 224, x = idx - kk * 224;
        lds[x * KK + kk] = src[(size_t)b * (KK * NPIX_B) + kk * NPIX_B + y * 224 + x];
    }
    __syncthreads();
    float* d2 = dst + (size_t)(b * 224 + y) * 224 * KK;
    for (int idx = threadIdx.x; idx < 224 * KK; idx += 256) d2[idx] = lds[idx];
}

// ---------------- one directional sweep (224 serial steps) ----------------
// One row (b, mm) per 64-lane wave. lane kk=lane&31: label k=kk for kk<21;
// lanes kk>=21 are NORM lanes (Vk:=Vmin) whose u == min_k(u) bit-exactly
// (validated round 10: min_k u == min_k' fma(ew, Vmin[k'], tmp[k'])).
// Recurrence runs UN-normalized (u); stored n = u - minu is the reference
// message exactly (min-plus shift invariance).
// Per step: tmp = fma(rho,u,pre); 21x readlane-broadcast of tmp;
//           u = min3-tree of fma(ew, Vk[t], bt);  minu = readlane(u, 21);
//           n = u - minu  (store masked to kk<21).
template<int D, bool VA, bool VB, bool VO, bool FUSE>
__global__ __launch_bounds__(64, 1)
void sweep_kernel(const float* __restrict__ unt,
                  const float* __restrict__ msA,   // msgs[other1]
                  const float* __restrict__ msB,   // msgs[other2]
                  const float* __restrict__ msO,   // msgs[opp]
                  float*       __restrict__ msD,   // msgs[D] (written unless FUSE)
                  const float* __restrict__ ewp,   // edge_weights (4,4,224,224)
                  const float* __restrict__ Vp,    // (21,21)
                  float*       __restrict__ outp)  // final output (FUSE only)
{
    const int lane = threadIdx.x;
    const int r    = blockIdx.x;         // 0..895
    const int b    = r / 224;
    const int mm   = r % 224;            // y for D=0,1 ; x for D=2,3
    const int kk   = lane & 31;
    const bool act = (kk < KK);          // label lane?
    const int k    = act ? kk : (KK - 1);

    // Vk[t] = V[t][k] for label lanes; Vmin[t] = min_k V[t][k] for norm lanes
    float Vk[KK];
#pragma unroll
    for (int t = 0; t < KK; ++t) {
        float vk = Vp[t * KK + k];
        if (!act) {
            float mv = Vp[t * KK + 0];
#pragma unroll
            for (int q = 1; q < KK; ++q) mv = fminf(mv, Vp[t * KK + q]);
            vk = mv;
        }
        Vk[t] = vk;
    }

    int pix0, sp;
    if (D == 0)      { pix0 = (b * 224 + mm) * 224;        sp = 1;    }
    else if (D == 1) { pix0 = (b * 224 + mm) * 224 + 223;  sp = -1;   }
    else if (D == 2) { pix0 = b * NPIX_B + mm;             sp = 224;  }
    else             { pix0 = b * NPIX_B + 223 * 224 + mm; sp = -224; }
    const int ewb = (b * 4 + D) * NPIX_B + (pix0 - b * NPIX_B);

    // prefetch: pre = rho*(un+ma+mb+mo) - mo (= base[i-1]); s3 for FUSE output
    float Apre[8], Aew[8], As3[8] = {};
    float Bpre[8], Bew[8], Bs3[8] = {};

#define LDC(P, c)                                                         \
    {                                                                     \
        _Pragma("unroll")                                                 \
        for (int t = 0; t < 8; ++t) {                                     \
            int i  = (c) * 8 + t;                                         \
            int ib = i - 1; if (ib < 0) ib = 0;                           \
            int o  = (pix0 + ib * sp) * KK + k;                           \
            float un = unt[o];                                            \
            float ma = VA ? msA[o] : 0.0f;                                \
            float mb = VB ? msB[o] : 0.0f;                                \
            float mo = VO ? msO[o] : 0.0f;                                \
            float s  = (un + ma) + (mb + mo);                             \
            P##pre[t] = fmaf(0.5f, s, -mo);                               \
            if constexpr (FUSE) P##s3[t] = s;                             \
            P##ew[t] = ewp[ewb + i * sp];                                 \
        }                                                                 \
    }

    float u = 0.0f, nprev = 0.0f;

    auto step = [&](float pre, float s3v, float ewi, int i) {
        if constexpr (FUSE) {                 // D==3: out at scan pos i-1 -> y=224-i
            if (i > 0 && act)
                outp[((b * KK + k) * 224 + (224 - i)) * 224 + mm] = s3v + nprev;
        }
        if (i == 0) {
            u = 0.0f; nprev = 0.0f;
            if (!FUSE && act) msD[pix0 * KK + k] = 0.0f;
            return;
        }
        float tmp = fmaf(0.5f, u, pre);       // base_prev + rho*u_prev
        int   ti  = __float_as_int(tmp);
        float c[KK];
#pragma unroll
        for (int t = 0; t < KK; ++t)
            c[t] = fmaf(ewi, Vk[t],
                        __int_as_float(__builtin_amdgcn_readlane(ti, t)));
        float c0 = min3f(c[0],  c[1],  c[2]);
        float c1 = min3f(c[3],  c[4],  c[5]);
        float c2 = min3f(c[6],  c[7],  c[8]);
        float c3 = min3f(c[9],  c[10], c[11]);
        float c4 = min3f(c[12], c[13], c[14]);
        float c5 = min3f(c[15], c[16], c[17]);
        float c6 = min3f(c[18], c[19], c[20]);
        u = min3f(min3f(c0, c1, c2), min3f(c3, c4, c5), c6);
        // norm lanes (kk>=21) computed u == min_k(u); broadcast from lane 21
        float minu = __int_as_float(
            __builtin_amdgcn_readlane(__float_as_int(u), KK));
        float n = u - minu;                   // == u - min_k(u), bit-exact
        if (!FUSE && act) msD[(pix0 + i * sp) * KK + k] = n;
        nprev = n;
    };

    LDC(A, 0);
    for (int cc = 0; cc < 28; cc += 2) {
        LDC(B, cc + 1);
#pragma unroll
        for (int t = 0; t < 8; ++t)
            step(Apre[t], As3[t], Aew[t], cc * 8 + t);
        if (cc + 2 < 28) LDC(A, cc + 2);
#pragma unroll
        for (int t = 0; t < 8; ++t)
            step(Bpre[t], Bs3[t], Bew[t], (cc + 1) * 8 + t);
    }
    if constexpr (FUSE) {
        // tail: scan pos 223 -> pixel y=0, x=mm
        int o = (pix0 + 223 * sp) * KK + k;
        float s3 = (unt[o] + msA[o]) + (msB[o] + msO[o]);
        if (act)
            outp[((b * KK + k) * 224 + 0) * 224 + mm] = s3 + nprev;
    }
#undef LDC
    (void)lane;
}

extern "C" void kernel_launch(void* const* d_in, const int* in_sizes, int n_in,
                              void* d_out, int out_size, void* d_ws, size_t ws_size,
                              hipStream_t stream)
{
    const float* unary = (const float*)d_in[0];
    const float* ew    = (const float*)d_in[1];
    const float* V     = (const float*)d_in[2];
    float* out = (float*)d_out;

    float* w   = (float*)d_ws;
    float* ms0 = w;
    float* ms1 = w + (size_t)NELEM;
    float* ms2 = w + (size_t)NELEM * 2;
    float* ms3 = w + (size_t)NELEM * 3;
    float* unt = w + (size_t)NELEM * 4;

    transpose_unary<<<dim3(896), dim3(256), 0, stream>>>(unary, unt);

    dim3 gS(896), bS(64);
    // iteration 0 (unwritten messages are provably zero -> elide loads;
    // ws is 0xAA-poisoned so elision is REQUIRED, not an optimization)
    sweep_kernel<0, false, false, false, false><<<gS, bS, 0, stream>>>(unt, ms2, ms3, ms1, ms0, ew, V, nullptr);
    sweep_kernel<1, false, false, true,  false><<<gS, bS, 0, stream>>>(unt, ms2, ms3, ms0, ms1, ew, V, nullptr);
    sweep_kernel<2, true,  true,  false, false><<<gS, bS, 0, stream>>>(unt, ms0, ms1, ms3, ms2, ew, V, nullptr);
    sweep_kernel<3, true,  true,  true,  false><<<gS, bS, 0, stream>>>(unt, ms0, ms1, ms2, ms3, ew, V, nullptr);
    // iteration 1 (all valid); last sweep fuses the final output
    sweep_kernel<0, true,  true,  true,  false><<<gS, bS, 0, stream>>>(unt, ms2, ms3, ms1, ms0, ew, V, nullptr);
    sweep_kernel<1, true,  true,  true,  false><<<gS, bS, 0, stream>>>(unt, ms2, ms3, ms0, ms1, ew, V, nullptr);
    sweep_kernel<2, true,  true,  true,  false><<<gS, bS, 0, stream>>>(unt, ms0, ms1, ms3, ms2, ew, V, nullptr);
    sweep_kernel<3, true,  true,  true,  true ><<<gS, bS, 0, stream>>>(unt, ms0, ms1, ms2, ms3, ew, V, out);
}